// Round 1
// baseline (1110.335 us; speedup 1.0000x reference)
//
#include <hip/hip_runtime.h>

#define IC 128
#define OC 256
#define KS 3
#define RR 64
#define CCOLS 64
#define HO 62
#define WO 62
#define NBATCH 16

// Densify the conditional bias into d_ws[0..255].
__global__ void bias_kernel(const int* __restrict__ bias_index,
                            const float* __restrict__ bias_value,
                            float* __restrict__ bias_dense, int nbias) {
    int t = threadIdx.x;
    if (t < OC) bias_dense[t] = 0.f;
    __syncthreads();
    if (t < nbias) {
        // indices are distinct by construction; atomicAdd is contention-free
        // and deterministic here, but also correct if duplicates ever appear.
        atomicAdd(&bias_dense[bias_index[t]], bias_value[t]);
    }
}

// One thread computes 4 consecutive x-outputs of one (b, oc, y).
// Block: 256 threads = 16 x-groups x 16 rows. Grid: (4 row-tiles, OC, B).
__global__ __launch_bounds__(256) void reconv_kernel(
    const float* __restrict__ images,
    const float* __restrict__ weight_value,
    const int* __restrict__ image_weight_index,
    const int* __restrict__ filter_lengths,
    const int* __restrict__ start_points,
    const float* __restrict__ bias_dense,
    float* __restrict__ out)
{
    const int tile = blockIdx.x;        // 0..3
    const int oc   = blockIdx.y;
    const int b    = blockIdx.z;
    const int t    = threadIdx.x;
    const int jr   = t & 15;            // x-group within row
    const int yr   = t >> 4;            // row within tile
    const int y    = tile * 16 + yr;
    if (y >= HO) return;
    // Last group overlaps (58..61 vs 56..59): duplicate identical writes, and
    // keeps the max image flat offset at 524287 < IC*RR*CCOLS (no OOB reads).
    const int colb = (4 * jr > WO - 4) ? (WO - 4) : (4 * jr);

    const float* __restrict__ img = images + (size_t)b * (IC * RR * CCOLS);
    const int sp  = start_points[oc];   // wave-uniform -> scalar loads
    const int len = filter_lengths[oc];
    const int off = y * CCOLS + colb;

    float a0 = 0.f, a1 = 0.f, a2 = 0.f, a3 = 0.f;
    #pragma unroll 8
    for (int k = 0; k < len; ++k) {
        const float w  = weight_value[sp + k];        // uniform -> s_load
        const int   ix = image_weight_index[sp + k];  // uniform -> s_load
        const float* __restrict__ p = img + ix + off; // uniform base + lane off
        const float v0 = p[0];
        const float v1 = p[1];
        const float v2 = p[2];
        const float v3 = p[3];
        a0 = fmaf(w, v0, a0);
        a1 = fmaf(w, v1, a1);
        a2 = fmaf(w, v2, a2);
        a3 = fmaf(w, v3, a3);
    }

    const float bs = bias_dense[oc];
    float* __restrict__ o = out + (((size_t)b * OC + oc) * HO + y) * WO + colb;
    o[0] = a0 + bs;
    o[1] = a1 + bs;
    o[2] = a2 + bs;
    o[3] = a3 + bs;
}

extern "C" void kernel_launch(void* const* d_in, const int* in_sizes, int n_in,
                              void* d_out, int out_size, void* d_ws, size_t ws_size,
                              hipStream_t stream) {
    const float* images             = (const float*)d_in[0];
    const float* weight_value       = (const float*)d_in[1];
    const int*   image_weight_index = (const int*)d_in[2];
    const int*   filter_lengths     = (const int*)d_in[3];
    const int*   start_points       = (const int*)d_in[4];
    const int*   bias_index         = (const int*)d_in[5];
    const float* bias_value         = (const float*)d_in[6];
    float* out        = (float*)d_out;
    float* bias_dense = (float*)d_ws;   // 256 floats of scratch

    bias_kernel<<<1, 256, 0, stream>>>(bias_index, bias_value, bias_dense,
                                       in_sizes[5]);

    dim3 grid(4, OC, NBATCH);
    reconv_kernel<<<grid, 256, 0, stream>>>(images, weight_value,
                                            image_weight_index, filter_lengths,
                                            start_points, bias_dense, out);
}

// Round 2
// 103.193 us; speedup vs baseline: 10.7598x; 10.7598x over previous
//
#include <hip/hip_runtime.h>

#define IC 128
#define OC 256
#define RR 64
#define CCOLS 64
#define HO 62
#define WO 62
#define NB 16

// dense bf16 weights: W9T[kpos][oc][c], kpos = ky*3+kx
#define W9T_ELEMS (9 * OC * IC)
#define W9T_BYTES (W9T_ELEMS * 2)

typedef __bf16 bf16x8 __attribute__((ext_vector_type(8)));
typedef float f32x4 __attribute__((ext_vector_type(4)));

__device__ __forceinline__ unsigned short f2bf(float f) {
    unsigned u = __builtin_bit_cast(unsigned, f);
    u += 0x7FFFu + ((u >> 16) & 1u);   // round-to-nearest-even
    return (unsigned short)(u >> 16);
}

// Scatter sparse taps into dense bf16 W9T[kpos][oc][c]. Taps are distinct per
// oc by construction -> plain stores, no atomics. W9T pre-zeroed via memset.
__global__ void prep_weights(const float* __restrict__ wv,
                             const int* __restrict__ iwi,
                             const int* __restrict__ flen,
                             const int* __restrict__ sp,
                             unsigned short* __restrict__ W9T) {
    const int oc = blockIdx.x;
    const int s = sp[oc];
    const int n = flen[oc];
    for (int t = threadIdx.x; t < n; t += blockDim.x) {
        const int ix = iwi[s + t];          // c*4096 + ky*64 + kx
        const int c = ix >> 12;
        const int rem = ix & 4095;
        const int ky = rem >> 6, kx = rem & 63;
        W9T[((ky * 3 + kx) * OC + oc) * IC + c] = f2bf(wv[s + t]);
    }
}

__global__ void bias_kernel(const int* __restrict__ bias_index,
                            const float* __restrict__ bias_value,
                            float* __restrict__ bias_dense, int nbias) {
    int t = threadIdx.x;
    if (t < OC) bias_dense[t] = 0.f;
    __syncthreads();
    if (t < nbias) atomicAdd(&bias_dense[bias_index[t]], bias_value[t]);
}

// Block = one output row (b, y) x all 256 oc. 512 threads = 8 waves.
// Wave w: oc in [32w, 32w+32) (2 m-tiles), x in [0,64) (4 n-tiles).
// LDS: image rows y..y+2, x-major bf16 [3][64x][128c], XOR-swizzled.
__global__ __launch_bounds__(512) void conv_mfma(
    const float* __restrict__ images,
    const unsigned short* __restrict__ W9T,
    const float* __restrict__ bias_dense,
    float* __restrict__ out)
{
    const int y = blockIdx.x;
    const int b = blockIdx.y;
    const int t = threadIdx.x;
    const int w = t >> 6;
    const int l = t & 63;
    const int lq = l >> 4, lr = l & 15;

    __shared__ unsigned char lds[3 * 64 * 256];   // 49152 B

    const float* __restrict__ imgb = images + (size_t)b * (IC * RR * CCOLS);

    // ---- stage 3 image rows, fp32 -> bf16, transposed to [x][c] w/ swizzle ----
    {
        const int xg = (t & 15) << 2;   // 4 consecutive x per thread
        const int cp = t >> 4;          // 0..31 channel-pair index
        #pragma unroll
        for (int p = 0; p < 6; ++p) {
            const int krow = p >> 1;
            const int c = ((p & 1) << 6) + (cp << 1);       // even channel
            const float* p0 = imgb + c * (RR * CCOLS) + (y + krow) * CCOLS + xg;
            const float4 r0 = *(const float4*)p0;
            const float4 r1 = *(const float4*)(p0 + RR * CCOLS);
            const float a0[4] = {r0.x, r0.y, r0.z, r0.w};
            const float a1[4] = {r1.x, r1.y, r1.z, r1.w};
            #pragma unroll
            for (int i = 0; i < 4; ++i) {
                const int x = xg + i;
                const unsigned v = (unsigned)f2bf(a0[i]) | ((unsigned)f2bf(a1[i]) << 16);
                *(unsigned*)(lds + krow * 16384 + x * 256 +
                             ((c * 2) ^ ((x & 7) << 4))) = v;
            }
        }
    }
    __syncthreads();

    f32x4 acc[2][4] = {};
    const int ocw = 32 * w;

    for (int kpos = 0; kpos < 9; ++kpos) {
        const int ky = kpos / 3, kx = kpos % 3;
        const unsigned short* __restrict__ Wk = W9T + kpos * (OC * IC);
        const unsigned char* __restrict__ row = lds + ky * 16384;
        #pragma unroll
        for (int c0 = 0; c0 < IC; c0 += 32) {
            const int cl = c0 + 8 * lq;             // this lane's k-slice base
            bf16x8 af[2];
            #pragma unroll
            for (int m = 0; m < 2; ++m)
                af[m] = *(const bf16x8*)(Wk + (ocw + 16 * m + lr) * IC + cl);
            bf16x8 bfr[4];
            #pragma unroll
            for (int n = 0; n < 4; ++n) {
                int x = 16 * n + lr + kx;
                x = x > 63 ? 63 : x;    // pad lanes: dup col 63 (discarded)
                bfr[n] = *(const bf16x8*)(row + x * 256 +
                                          ((cl * 2) ^ ((x & 7) << 4)));
            }
            #pragma unroll
            for (int m = 0; m < 2; ++m) {
                #pragma unroll
                for (int n = 0; n < 4; ++n)
                    acc[m][n] = __builtin_amdgcn_mfma_f32_16x16x32_bf16(
                        af[m], bfr[n], acc[m][n], 0, 0, 0);
            }
        }
    }

    // ---- epilogue: bias + store (C/D: col = lane&15, row = 4*lq + r) ----
    #pragma unroll
    for (int m = 0; m < 2; ++m) {
        const int ocb = ocw + 16 * m + 4 * lq;
        float bv[4];
        #pragma unroll
        for (int r = 0; r < 4; ++r) bv[r] = bias_dense[ocb + r];
        #pragma unroll
        for (int n = 0; n < 4; ++n) {
            const int x = 16 * n + lr;
            if (x < WO) {
                #pragma unroll
                for (int r = 0; r < 4; ++r)
                    out[(((size_t)b * OC + ocb + r) * HO + y) * WO + x] =
                        acc[m][n][r] + bv[r];
            }
        }
    }
}

extern "C" void kernel_launch(void* const* d_in, const int* in_sizes, int n_in,
                              void* d_out, int out_size, void* d_ws, size_t ws_size,
                              hipStream_t stream) {
    const float* images             = (const float*)d_in[0];
    const float* weight_value       = (const float*)d_in[1];
    const int*   image_weight_index = (const int*)d_in[2];
    const int*   filter_lengths     = (const int*)d_in[3];
    const int*   start_points       = (const int*)d_in[4];
    const int*   bias_index         = (const int*)d_in[5];
    const float* bias_value         = (const float*)d_in[6];
    float* out = (float*)d_out;

    unsigned short* W9T = (unsigned short*)d_ws;
    float* bias_dense = (float*)((char*)d_ws + W9T_BYTES);

    hipMemsetAsync(d_ws, 0, W9T_BYTES, stream);
    prep_weights<<<OC, 256, 0, stream>>>(weight_value, image_weight_index,
                                         filter_lengths, start_points, W9T);
    bias_kernel<<<1, 256, 0, stream>>>(bias_index, bias_value, bias_dense,
                                       in_sizes[5]);

    dim3 grid(HO, NB);
    conv_mfma<<<grid, 512, 0, stream>>>(images, W9T, bias_dense, out);
}